// Round 1
// baseline (152.207 us; speedup 1.0000x reference)
//
#include <hip/hip_runtime.h>

// LrDistance: out[s,m,n] = invalid ? 100 : |lr[s,m,n] + bilinear(rl[s], gx, gy)|
// grid_sample semantics: padding_mode='zeros', align_corners=False.
// ix = ((gx+1)*N - 1)*0.5 with gx = 2*(n - lr)/(N-1) - 1
// iy = ((gy+1)*M - 1)*0.5 with gy = 2*m/(M-1) - 1   (depends only on m)
// invalid = (xr >= N) || (xr < 0), xr = n - lr.

constexpr int S = 16;
constexpr int M = 768;
constexpr int N = 1024;

__global__ __launch_bounds__(256) void lr_distance_kernel(
    const float* __restrict__ lr,
    const float* __restrict__ rl,
    float* __restrict__ out)
{
    const long long t    = (long long)blockIdx.x * blockDim.x + threadIdx.x;
    const long long base = t * 4;                 // 4 contiguous elements per thread
    const int n0    = (int)(base & (N - 1));      // N = 1024 (pow2)
    const int rowid = (int)(base >> 10);          // base / N
    const int s     = rowid / M;
    const int m     = rowid - s * M;

    const float* rlp = rl + (size_t)s * M * N;

    // --- y interpolation: constant per row (match reference op order) ---
    const float gy  = (2.0f * (float)m) / (float)(M - 1) - 1.0f;
    const float iy  = ((gy + 1.0f) * (float)M - 1.0f) * 0.5f;
    const float y0f = floorf(iy);
    const float y1f = y0f + 1.0f;
    const float wy1 = iy - y0f;
    const float wy0 = 1.0f - wy1;
    const bool  y0in = (y0f >= 0.0f) && (y0f <= (float)(M - 1));
    const bool  y1in = (y1f >= 0.0f) && (y1f <= (float)(M - 1));
    const int   y0c  = min(max((int)y0f, 0), M - 1);
    const int   y1c  = min(max((int)y1f, 0), M - 1);
    const float* row0 = rlp + (size_t)y0c * N;
    const float* row1 = rlp + (size_t)y1c * N;

    const float4 d4 = *reinterpret_cast<const float4*>(lr + base);
    float dv[4] = {d4.x, d4.y, d4.z, d4.w};
    float ov[4];

#pragma unroll
    for (int k = 0; k < 4; ++k) {
        const float d  = dv[k];
        const float xr = (float)(n0 + k) - d;
        // match reference op sequence exactly (floor-boundary sensitive)
        const float gx = (2.0f * xr) / (float)(N - 1) - 1.0f;
        const float ix = ((gx + 1.0f) * (float)N - 1.0f) * 0.5f;
        const float x0f = floorf(ix);
        const float x1f = x0f + 1.0f;
        const float wx1 = ix - x0f;
        const float wx0 = 1.0f - wx1;
        const int   x0  = (int)x0f;
        const int   x1  = x0 + 1;
        const bool  x0in = (x0f >= 0.0f) && (x0f <= (float)(N - 1));
        const bool  x1in = (x1f >= 0.0f) && (x1f <= (float)(N - 1));
        const int   x0c  = min(max(x0, 0), N - 1);
        const int   x1c  = min(max(x1, 0), N - 1);

        const float v00 = (y0in && x0in) ? row0[x0c] : 0.0f;
        const float v01 = (y0in && x1in) ? row0[x1c] : 0.0f;
        const float v10 = (y1in && x0in) ? row1[x0c] : 0.0f;
        const float v11 = (y1in && x1in) ? row1[x1c] : 0.0f;

        const float warped = v00 * wy0 * wx0 + v01 * wy0 * wx1
                           + v10 * wy1 * wx0 + v11 * wy1 * wx1;

        const bool invalid = (xr >= (float)N) || (xr < 0.0f);
        ov[k] = invalid ? 100.0f : fabsf(d + warped);
    }

    *reinterpret_cast<float4*>(out + base) = make_float4(ov[0], ov[1], ov[2], ov[3]);
}

extern "C" void kernel_launch(void* const* d_in, const int* in_sizes, int n_in,
                              void* d_out, int out_size, void* d_ws, size_t ws_size,
                              hipStream_t stream) {
    const float* lr  = (const float*)d_in[0];   // disps_lr [16,1,768,1024] fp32
    const float* rl  = (const float*)d_in[1];   // disps_rl [16,1,768,1024] fp32
    float*       out = (float*)d_out;

    const long long total   = (long long)S * M * N;  // 12,582,912 (divisible by 4*256)
    const int       threads = 256;
    const int       blocks  = (int)(total / 4 / threads);  // 12288

    lr_distance_kernel<<<blocks, threads, 0, stream>>>(lr, rl, out);
}

// Round 2
// 135.492 us; speedup vs baseline: 1.1234x; 1.1234x over previous
//
#include <hip/hip_runtime.h>

// LrDistance: out[s,m,n] = invalid ? 100 : |lr[s,m,n] + bilinear(rl[s], gx, gy)|
// grid_sample: padding_mode='zeros', align_corners=False.
//   ix = xr*N/(N-1) - 0.5 (computed via reference op order), xr = n - lr
//   iy depends only on m -> y0/y1 are block-constant.
// R2 strategy: one block per (s,m) row; stage rl rows y0c,y1c into LDS with
// coalesced float4 loads; all bilinear gathers hit LDS (kills the VMEM
// instruction-issue bottleneck seen in R1: 16 scattered dword loads/thread).

constexpr int S = 16;
constexpr int M = 768;
constexpr int N = 1024;

__global__ __launch_bounds__(256) void lr_distance_kernel(
    const float* __restrict__ lr,
    const float* __restrict__ rl,
    float* __restrict__ out)
{
    __shared__ float row0s[N];
    __shared__ float row1s[N];

    const int rowid = blockIdx.x;        // s*M + m
    const int s = rowid / M;
    const int m = rowid - s * M;
    const int tid = threadIdx.x;

    const float* rlp = rl + (size_t)s * M * N;

    // --- y interpolation: constant per row (match reference op order) ---
    const float gy  = (2.0f * (float)m) / (float)(M - 1) - 1.0f;
    const float iy  = ((gy + 1.0f) * (float)M - 1.0f) * 0.5f;
    const float y0f = floorf(iy);
    const float y1f = y0f + 1.0f;
    const float wy1 = iy - y0f;
    const float wy0 = 1.0f - wy1;
    const bool  y0in = (y0f >= 0.0f) && (y0f <= (float)(M - 1));
    const bool  y1in = (y1f >= 0.0f) && (y1f <= (float)(M - 1));
    const int   y0c  = min(max((int)y0f, 0), M - 1);
    const int   y1c  = min(max((int)y1f, 0), M - 1);

    // --- stage the two rl rows into LDS (coalesced float4) ---
    {
        const float4 r0 = *reinterpret_cast<const float4*>(rlp + (size_t)y0c * N + tid * 4);
        const float4 r1 = *reinterpret_cast<const float4*>(rlp + (size_t)y1c * N + tid * 4);
        *reinterpret_cast<float4*>(&row0s[tid * 4]) = r0;
        *reinterpret_cast<float4*>(&row1s[tid * 4]) = r1;
    }
    __syncthreads();

    const size_t base = (size_t)rowid * N + tid * 4;
    const int n0 = tid * 4;

    const float4 d4 = *reinterpret_cast<const float4*>(lr + base);
    float dv[4] = {d4.x, d4.y, d4.z, d4.w};
    float ov[4];

#pragma unroll
    for (int k = 0; k < 4; ++k) {
        const float d  = dv[k];
        const float xr = (float)(n0 + k) - d;
        // match reference op sequence exactly (floor-boundary sensitive)
        const float gx = (2.0f * xr) / (float)(N - 1) - 1.0f;
        const float ix = ((gx + 1.0f) * (float)N - 1.0f) * 0.5f;
        const float x0f = floorf(ix);
        const float x1f = x0f + 1.0f;
        const float wx1 = ix - x0f;
        const float wx0 = 1.0f - wx1;
        const int   x0  = (int)x0f;
        const bool  x0in = (x0f >= 0.0f) && (x0f <= (float)(N - 1));
        const bool  x1in = (x1f >= 0.0f) && (x1f <= (float)(N - 1));
        const int   x0c  = min(max(x0, 0), N - 1);
        const int   x1c  = min(max(x0 + 1, 0), N - 1);

        const float v00 = (y0in && x0in) ? row0s[x0c] : 0.0f;
        const float v01 = (y0in && x1in) ? row0s[x1c] : 0.0f;
        const float v10 = (y1in && x0in) ? row1s[x0c] : 0.0f;
        const float v11 = (y1in && x1in) ? row1s[x1c] : 0.0f;

        const float warped = v00 * wy0 * wx0 + v01 * wy0 * wx1
                           + v10 * wy1 * wx0 + v11 * wy1 * wx1;

        const bool invalid = (xr >= (float)N) || (xr < 0.0f);
        ov[k] = invalid ? 100.0f : fabsf(d + warped);
    }

    *reinterpret_cast<float4*>(out + base) = make_float4(ov[0], ov[1], ov[2], ov[3]);
}

extern "C" void kernel_launch(void* const* d_in, const int* in_sizes, int n_in,
                              void* d_out, int out_size, void* d_ws, size_t ws_size,
                              hipStream_t stream) {
    const float* lr  = (const float*)d_in[0];   // disps_lr [16,1,768,1024] fp32
    const float* rl  = (const float*)d_in[1];   // disps_rl [16,1,768,1024] fp32
    float*       out = (float*)d_out;

    const int blocks  = S * M;   // one block per row: 12288
    const int threads = 256;     // 4 elements per thread

    lr_distance_kernel<<<blocks, threads, 0, stream>>>(lr, rl, out);
}

// Round 4
// 135.360 us; speedup vs baseline: 1.1245x; 1.0010x over previous
//
#include <hip/hip_runtime.h>

// LrDistance: out[s,m,n] = invalid ? 100 : |lr[s,m,n] + bilinear(rl[s], gx, gy)|
// grid_sample: padding_mode='zeros', align_corners=False.
//   ix = xr*N/(N-1) - 0.5 (reference op order), xr = n - lr
//   iy depends only on m -> y0/y1/wy are block-constant.
// R3: pre-blend the two rl rows into ONE LDS row with the y-weights folded in
//   br[x] = wy0z*row0[x] + wy1z*row1[x]   (wy*z carry the zeros-padding mask)
// -> 2 LDS reads + 2 mul/fma per element (was 4 reads + 8 mul), LDS 8->4 KB.
// Re-association error <= ~1e-4 vs reference (threshold 2.0). Non-temporal
// output stores keep the write stream from evicting rl in L2.
// R4 fix: __builtin_nontemporal_store needs a native ext_vector type, not
// HIP_vector_type<float,4>.

constexpr int S = 16;
constexpr int M = 768;
constexpr int N = 1024;

typedef float vfloat4 __attribute__((ext_vector_type(4)));

__global__ __launch_bounds__(256) void lr_distance_kernel(
    const float* __restrict__ lr,
    const float* __restrict__ rl,
    float* __restrict__ out)
{
    __shared__ float br[N];   // y-blended rl row

    const int rowid = blockIdx.x;        // s*M + m
    const int s = rowid / M;
    const int m = rowid - s * M;
    const int tid = threadIdx.x;

    const float* rlp = rl + (size_t)s * M * N;

    // --- y interpolation: block-uniform (match reference op order) ---
    const float gy  = (2.0f * (float)m) / (float)(M - 1) - 1.0f;
    const float iy  = ((gy + 1.0f) * (float)M - 1.0f) * 0.5f;
    const float y0f = floorf(iy);
    const float y1f = y0f + 1.0f;
    const float wy1 = iy - y0f;
    const float wy0 = 1.0f - wy1;
    const bool  y0in = (y0f >= 0.0f) && (y0f <= (float)(M - 1));
    const bool  y1in = (y1f >= 0.0f) && (y1f <= (float)(M - 1));
    const float wy0z = y0in ? wy0 : 0.0f;   // fold zeros-padding into weight
    const float wy1z = y1in ? wy1 : 0.0f;
    const int   y0c  = min(max((int)y0f, 0), M - 1);
    const int   y1c  = min(max((int)y1f, 0), M - 1);

    // --- stage: load both rows (float4), blend in registers, one LDS write ---
    {
        const vfloat4 r0 = *reinterpret_cast<const vfloat4*>(rlp + (size_t)y0c * N + tid * 4);
        const vfloat4 r1 = *reinterpret_cast<const vfloat4*>(rlp + (size_t)y1c * N + tid * 4);
        vfloat4 b = wy0z * r0 + wy1z * r1;
        *reinterpret_cast<vfloat4*>(&br[tid * 4]) = b;
    }
    __syncthreads();

    const size_t base = (size_t)rowid * N + tid * 4;
    const int n0 = tid * 4;

    const vfloat4 d4 = *reinterpret_cast<const vfloat4*>(lr + base);
    float dv[4] = {d4.x, d4.y, d4.z, d4.w};
    float ov[4];

#pragma unroll
    for (int k = 0; k < 4; ++k) {
        const float d  = dv[k];
        const float xr = (float)(n0 + k) - d;
        // match reference op sequence exactly (floor-boundary sensitive)
        const float gx = (2.0f * xr) / (float)(N - 1) - 1.0f;
        const float ix = ((gx + 1.0f) * (float)N - 1.0f) * 0.5f;
        const float x0f = floorf(ix);
        const float x1f = x0f + 1.0f;
        const float wx1 = ix - x0f;
        const float wx0 = 1.0f - wx1;
        const int   x0  = (int)x0f;
        // d >= 0 -> ix <= 1023.5 -> x0 <= N-1: upper clamp on x0 is dead.
        const int   x0c  = max(x0, 0);
        const int   x1c  = min(max(x0 + 1, 0), N - 1);
        const bool  x0in = (x0f >= 0.0f);                              // x0f <= N-1 always
        const bool  x1in = (x1f >= 0.0f) && (x1f <= (float)(N - 1));

        const float a  = x0in ? br[x0c] : 0.0f;
        const float bb = x1in ? br[x1c] : 0.0f;
        const float warped = wx0 * a + wx1 * bb;

        const bool invalid = (xr >= (float)N) || (xr < 0.0f);
        ov[k] = invalid ? 100.0f : fabsf(d + warped);
    }

    vfloat4 o4;
    o4.x = ov[0]; o4.y = ov[1]; o4.z = ov[2]; o4.w = ov[3];
    __builtin_nontemporal_store(o4, reinterpret_cast<vfloat4*>(out + base));
}

extern "C" void kernel_launch(void* const* d_in, const int* in_sizes, int n_in,
                              void* d_out, int out_size, void* d_ws, size_t ws_size,
                              hipStream_t stream) {
    const float* lr  = (const float*)d_in[0];   // disps_lr [16,1,768,1024] fp32
    const float* rl  = (const float*)d_in[1];   // disps_rl [16,1,768,1024] fp32
    float*       out = (float*)d_out;

    const int blocks  = S * M;   // one block per row: 12288
    const int threads = 256;     // 4 elements per thread

    lr_distance_kernel<<<blocks, threads, 0, stream>>>(lr, rl, out);
}